// Round 2
// 474.940 us; speedup vs baseline: 1.0157x; 1.0157x over previous
//
#include <hip/hip_runtime.h>

#define B_  16
#define T_  2048
#define R_  256
#define NS_ 4

typedef unsigned short u16;
typedef __attribute__((ext_vector_type(8))) __bf16 bf16x8;
typedef __attribute__((ext_vector_type(4))) float f32x4;

__device__ __forceinline__ u16 f2bf(float f){
  union { float f; unsigned u; } x; x.f = f;
  unsigned r = x.u + 0x7FFFu + ((x.u >> 16) & 1u);
  return (u16)(r >> 16);
}
__device__ __forceinline__ float bf2f(u16 h){
  union { unsigned u; float f; } x; x.u = ((unsigned)h) << 16; return x.f;
}

// async global->LDS, 16B per lane. LDS dest must be wave-uniform base; HW
// writes lane i at base + i*16 (guide §5). Our chunk order matches that.
__device__ __forceinline__ void async_cp16(const void* g, void* l){
  __builtin_amdgcn_global_load_lds((__attribute__((address_space(1))) void*)g,
                                   (__attribute__((address_space(3))) void*)l,
                                   16, 0, 0);
}

// ---------------------------------------------------------------- convert
__global__ __launch_bounds__(256)
void cvt_kernel(const float* __restrict__ src, u16* __restrict__ dst, int n4){
  int i = blockIdx.x*256 + threadIdx.x;
  if (i >= n4) return;
  float4 f = ((const float4*)src)[i];
  ushort4 o;
  o.x = f2bf(f.x); o.y = f2bf(f.y); o.z = f2bf(f.z); o.w = f2bf(f.w);
  ((ushort4*)dst)[i] = o;
}

__global__ __launch_bounds__(256)
void zero_kernel(float* __restrict__ p, int n){
  int i = blockIdx.x*256 + threadIdx.x;
  if (i < n) p[i] = 0.0f;
}

// Zero the above-diagonal strips of P' that the 256-row pv A-tiles read but
// attn never writes: per (b,tT): rows [256tT, 256tT+128) x cols
// [256tT+128, 256tT+256). 4 MB total.
__global__ __launch_bounds__(256)
void pzero_kernel(u16* __restrict__ P){
  int blk = blockIdx.x;            // 0..127
  int b = blk & 15, tT = blk >> 4; // tT 0..7
  long long base = (long long)b*T_*T_ + (long long)(tT*256)*T_ + (tT*256 + 128);
  int r = threadIdx.x >> 1, h = threadIdx.x & 1;
  u16* p = P + base + (long long)r*T_ + h*64;
  uint4 z = {0u,0u,0u,0u};
  #pragma unroll
  for (int i=0;i<8;i++) ((uint4*)p)[i] = z;
}

// ------------------------------------------------- generic NT GEMM (bf16)
// C[m][n] = sum_k A[m][k]*B[n][k] + bias ; C stored bf16.
// z decode: n = z&3 (weight/bias select), b = z>>2 (batch select).
// biasMode 0: bias indexed by col (N). biasMode 1: bias indexed by row (M).
__global__ __launch_bounds__(256, 2)
void gemm_nt_bias(const u16* __restrict__ A, const u16* __restrict__ Bm,
                  u16* __restrict__ C, const float* __restrict__ bias,
                  int lda, int ldb, int ldc, int K,
                  long long sAn, long long sBb, long long sCz,
                  int sBiasN, int biasMode)
{
  __shared__ __align__(16) u16 As[128*32];
  __shared__ __align__(16) u16 Bs[128*32];
  int tid = threadIdx.x;
  int lane = tid & 63, wave = tid >> 6;
  int z = blockIdx.z;
  int nIdx = z & 3, bIdx = z >> 2;
  A    += (long long)nIdx * sAn;
  Bm   += (long long)bIdx * sBb;
  C    += (long long)z * sCz;
  bias += (long long)nIdx * sBiasN;
  int mBase = blockIdx.y * 128;
  int nBase = blockIdx.x * 128;
  int wm = (wave >> 1) * 64, wn = (wave & 1) * 64;
  int quad = lane >> 4, lc = lane & 15;

  f32x4 acc[4][4];
  #pragma unroll
  for (int i=0;i<4;i++)
    #pragma unroll
    for (int j=0;j<4;j++) acc[i][j] = (f32x4){0.f,0.f,0.f,0.f};

  for (int k0=0; k0<K; k0+=32){
    #pragma unroll
    for (int r=0;r<2;r++){
      int c = r*256 + tid;
      int row = c >> 2, col = (c & 3)*8;
      async_cp16(A  + (long long)(mBase+row)*lda + k0 + col, (void*)(As + (r*256 + wave*64)*8));
      async_cp16(Bm + (long long)(nBase+row)*ldb + k0 + col, (void*)(Bs + (r*256 + wave*64)*8));
    }
    __syncthreads();
    bf16x8 af[4], bfr[4];
    #pragma unroll
    for (int i=0;i<4;i++){
      af[i]  = *(const bf16x8*)(As + (wm + i*16 + lc)*32 + quad*8);
      bfr[i] = *(const bf16x8*)(Bs + (wn + i*16 + lc)*32 + quad*8);
    }
    #pragma unroll
    for (int i=0;i<4;i++)
      #pragma unroll
      for (int j=0;j<4;j++)
        acc[i][j] = __builtin_amdgcn_mfma_f32_16x16x32_bf16(af[i], bfr[j], acc[i][j], 0,0,0);
    __syncthreads();
  }
  // epilogue: C/D layout col=lane&15, row=quad*4+e (m89/m91 verified)
  #pragma unroll
  for (int i=0;i<4;i++){
    #pragma unroll
    for (int j=0;j<4;j++){
      int colG = nBase + wn + j*16 + lc;
      float bc = (biasMode==0) ? bias[colG] : 0.0f;
      #pragma unroll
      for (int e=0;e<4;e++){
        int rowG = mBase + wm + i*16 + quad*4 + e;
        float val = acc[i][j][e] + ((biasMode==0) ? bc : bias[rowG]);
        C[(long long)rowG*ldc + colG] = f2bf(val);
      }
    }
  }
}

// ------------------------------------- attention scores, single sweep
// One block per (b, 64-row t-tile, 128-col s-tile). No max subtraction:
// scores here are bounded (|v| ~< 10 << 88), so p' = exp(v) is overflow-safe
// and softmax = p'/sum(p') exactly. Masked (s>t or v==0) -> exp(-10000) = 0
// in fp32, matching the reference tril+where quirk. Row sums accumulate via
// fp32 atomicAdd into l[B][T]; pv_kernel divides by l in its epilogue.
__global__ __launch_bounds__(256, 4)
void attn_kernel(const u16* __restrict__ qp, const u16* __restrict__ kp,
                 u16* __restrict__ P, float* __restrict__ lsum)
{
  __shared__ __align__(16) u16 Qs[64*32];
  __shared__ __align__(16) u16 Ks[128*32];
  int tid = threadIdx.x, lane = tid & 63, wave = tid >> 6;
  int b = blockIdx.y;
  // heavy-first flat decode: t64 descending, c(t64)=t64/2+1 s-tiles
  int f = blockIdx.x;
  int t64 = 31;
  while (f >= (t64 >> 1) + 1){ f -= (t64 >> 1) + 1; t64--; }
  int sT = f;
  int tBase = t64 * 64;
  const u16* Q  = qp + ((long long)b*T_ + tBase) * R_;
  const u16* Kt = kp + (long long)b*T_*R_ + (long long)sT*128*R_;
  u16* Pb = P + (long long)b*T_*T_;
  const float scale = 0.0625f;     // 1/sqrt(256)
  int quad = lane >> 4, lc = lane & 15;
  int rowLoc = wave*16 + quad*4;

  f32x4 acc[8];
  #pragma unroll
  for (int j=0;j<8;j++) acc[j] = (f32x4){0.f,0.f,0.f,0.f};

  for (int k0=0;k0<R_;k0+=32){
    {
      int row = tid >> 2, col = (tid & 3)*8;
      async_cp16(Q + (long long)row*R_ + k0 + col, (void*)(Qs + (wave*64)*8));
    }
    #pragma unroll
    for (int r=0;r<2;r++){
      int c = r*256 + tid;
      int row = c >> 2, col = (c & 3)*8;
      async_cp16(Kt + (long long)row*R_ + k0 + col, (void*)(Ks + (r*256 + wave*64)*8));
    }
    __syncthreads();
    bf16x8 aq = *(const bf16x8*)(Qs + (wave*16 + lc)*32 + quad*8);
    #pragma unroll
    for (int j=0;j<8;j++){
      bf16x8 bk = *(const bf16x8*)(Ks + (j*16 + lc)*32 + quad*8);
      acc[j] = __builtin_amdgcn_mfma_f32_16x16x32_bf16(aq, bk, acc[j], 0,0,0);
    }
    __syncthreads();
  }

  int sCol0 = sT*128 + lc;
  #pragma unroll
  for (int e=0;e<4;e++){
    int t = tBase + rowLoc + e;
    long long ro = (long long)t * T_;
    float rs = 0.0f;
    #pragma unroll
    for (int j=0;j<8;j++){
      float v = acc[j][e]*scale;
      int s = sCol0 + j*16;
      if (s > t || v == 0.0f) v = -10000.0f;
      float p = __expf(v);            // exact 0 when masked
      rs += p;
      Pb[ro + s] = f2bf(p);
    }
    // sum across the 16 lc-lanes of this quad (they hold cols of row t)
    #pragma unroll
    for (int off=1; off<16; off<<=1)
      rs += __shfl_xor(rs, off, 64);
    if (lc == 0)
      atomicAdd(&lsum[b*T_ + t], rs);
  }
}

// --------------------------------------------------------------- PV GEMM
// out[b][n][t][r] = (1/l[t]) * sum_s P'[b][t][s] * VT[b][n*256+r][s]
// 256x256 tile, BK=64, 8 waves (2Mx4N), 512 threads, 8-phase schedule
// (T2 swizzle + T3/T4 counted vmcnt + T5 setprio per guide §5.5).
//
// LDS: per matrix 2 K-tile bufs x 2 k-halves x [256 rows][32 k] bf16
//   = 64 KB; A + B = 128 KB. Even K-tiles -> buf0, odd -> buf1.
// Phase (of 8 per iteration j covering K-tiles e=2j, o=2j+1):
//   p1 (e,h0,cuUp) stage A(o,h1) | p2 (e,h0,cuLo) stage B(o,h1)
//   p3 (e,h1,cuUp) stage A(e+2,h0) | p4 (e,h1,cuLo) stage B(e+2,h0)
//   p5 (o,h0,cuUp) stage A(e+2,h1) | p6 (o,h0,cuLo) stage B(e+2,h1)
//   p7 (o,h1,cuUp) stage A(o+2,h0) | p8 (o,h1,cuLo) stage B(o+2,h0)
// Every staged slot is dead as of the previous phase-end barrier; every
// read's producer stage is >=6 phases old; s_waitcnt vmcnt(8) at even
// phase ends retires exactly the producers of the phase after next.
// Swizzle: LDS 16B-chunk index c of row r holds global chunk c ^ v(r),
// v(r) = (r&3)^((r>>2)&3); applied on the per-lane GLOBAL address at
// stage time (LDS dest stays linear, rule #21) and on the ds_read addr.
// 64-lane ds_read_b128 is then 2-way bank aliased (free) vs 8-way before.
#define MF(A,Bx,C) __builtin_amdgcn_mfma_f32_16x16x32_bf16(A,Bx,C,0,0,0)
#define VM8 asm volatile("s_waitcnt vmcnt(8)" ::: "memory")
#define VM4 asm volatile("s_waitcnt vmcnt(4)" ::: "memory")
#define VM0 asm volatile("s_waitcnt vmcnt(0)" ::: "memory")
#define NOWT ((void)0)
#define NOSTG ((void)0)

#define STAGE_A(KT,KH) do { \
  const u16* sp_ = aG + (int)((KT)*64 + (KH)*32); \
  u16* dp_ = (u16*)lds + (((KT)&1)*16384 + (KH)*8192 + wave*512); \
  async_cp16(sp_ + stOff, dp_); \
  async_cp16(sp_ + stOff + 128*2048, dp_ + 4096); \
} while(0)
#define STAGE_B(KT,KH) do { \
  const u16* sp_ = bG + (int)((KT)*64 + (KH)*32); \
  u16* dp_ = (u16*)lds + (32768 + ((KT)&1)*16384 + (KH)*8192 + wave*512); \
  async_cp16(sp_ + stOff, dp_); \
  async_cp16(sp_ + stOff + 128*2048, dp_ + 4096); \
} while(0)

#define LDA_F(BUF,KH,CU,TI) (*(const bf16x8*)(&lds[(BUF)*16384 + (KH)*8192 + (rbA + (CU)*64 + (TI)*16)*32 + qSw]))
#define LDB_F(BUF,KH,JJ)    (*(const bf16x8*)(&lds[32768 + (BUF)*16384 + (KH)*8192 + (rbB + (JJ)*16)*32 + qSw]))

#define PHASE(BUF,KH,CU,STG,WT) do { \
  bf16x8 a0_ = LDA_F(BUF,KH,CU,0); \
  bf16x8 a1_ = LDA_F(BUF,KH,CU,1); \
  bf16x8 a2_ = LDA_F(BUF,KH,CU,2); \
  bf16x8 a3_ = LDA_F(BUF,KH,CU,3); \
  if ((CU)==0){ bF0 = LDB_F(BUF,KH,0); bF1 = LDB_F(BUF,KH,1); \
                bF2 = LDB_F(BUF,KH,2); bF3 = LDB_F(BUF,KH,3); } \
  STG; \
  asm volatile("" ::: "memory"); \
  __builtin_amdgcn_s_barrier(); \
  asm volatile("s_waitcnt lgkmcnt(0)" ::: "memory"); \
  __builtin_amdgcn_sched_barrier(0); \
  __builtin_amdgcn_s_setprio(1); \
  acc[(CU)*4+0][0]=MF(a0_,bF0,acc[(CU)*4+0][0]); \
  acc[(CU)*4+0][1]=MF(a0_,bF1,acc[(CU)*4+0][1]); \
  acc[(CU)*4+0][2]=MF(a0_,bF2,acc[(CU)*4+0][2]); \
  acc[(CU)*4+0][3]=MF(a0_,bF3,acc[(CU)*4+0][3]); \
  acc[(CU)*4+1][0]=MF(a1_,bF0,acc[(CU)*4+1][0]); \
  acc[(CU)*4+1][1]=MF(a1_,bF1,acc[(CU)*4+1][1]); \
  acc[(CU)*4+1][2]=MF(a1_,bF2,acc[(CU)*4+1][2]); \
  acc[(CU)*4+1][3]=MF(a1_,bF3,acc[(CU)*4+1][3]); \
  acc[(CU)*4+2][0]=MF(a2_,bF0,acc[(CU)*4+2][0]); \
  acc[(CU)*4+2][1]=MF(a2_,bF1,acc[(CU)*4+2][1]); \
  acc[(CU)*4+2][2]=MF(a2_,bF2,acc[(CU)*4+2][2]); \
  acc[(CU)*4+2][3]=MF(a2_,bF3,acc[(CU)*4+2][3]); \
  acc[(CU)*4+3][0]=MF(a3_,bF0,acc[(CU)*4+3][0]); \
  acc[(CU)*4+3][1]=MF(a3_,bF1,acc[(CU)*4+3][1]); \
  acc[(CU)*4+3][2]=MF(a3_,bF2,acc[(CU)*4+3][2]); \
  acc[(CU)*4+3][3]=MF(a3_,bF3,acc[(CU)*4+3][3]); \
  __builtin_amdgcn_s_setprio(0); \
  WT; \
  asm volatile("" ::: "memory"); \
  __builtin_amdgcn_s_barrier(); \
} while(0)

__global__ __launch_bounds__(512, 2)
void pv_kernel(const u16* __restrict__ P, const u16* __restrict__ VT,
               const float* __restrict__ lsum, float* __restrict__ out)
{
  __shared__ __align__(16) u16 lds[65536];   // 128 KB
  int tid = threadIdx.x, lane = tid & 63, wave = tid >> 6;
  // grid: 512 blocks. xcd = f&7; group g = (b,tT) with its 4 j-blocks on
  // adjacent dispatch slots of the same xcd slot (P-tile L2 reuse);
  // tT descending with dispatch (heavy-first, greedy-balanced).
  int f = blockIdx.x;
  int xcd = f & 7, s = f >> 3;
  int g = xcd + 8*(s >> 2);     // 0..127
  int jIdx = s & 3;             // 0..3 -> n index
  int b = g & 15;
  int tT = 7 - (g >> 4);        // 0..7, heavy first
  int t0abs = tT * 256;
  int nIt = 2*(tT + 1);         // iterations; K = 64*4*(tT+1)

  const u16* aG = P  + (long long)b*T_*T_ + (long long)t0abs*T_;
  const u16* bG = VT + (long long)b*1024*T_ + (long long)(jIdx*256)*T_;

  // staging per-lane constants: lane L writes LDS chunk (L&3) of row L>>2;
  // fetch global chunk (L&3)^v(row) so LDS slot (r,c) holds chunk c^v(r).
  int stRow = tid >> 2;
  int vSt = (stRow & 3) ^ ((stRow >> 2) & 3);
  int stOff = stRow*2048 + (((tid & 3) ^ vSt) << 3);

  // read-side per-lane constants
  int quad = lane >> 4, lc = lane & 15;
  int wm = wave >> 2, wn = wave & 3;             // 2M x 4N waves
  int vlc = (lc & 3) ^ ((lc >> 2) & 3);          // == v(row) for all frag rows
  int qSw = ((quad ^ vlc) << 3);
  int rbA = wm*128 + lc;
  int rbB = wn*64 + lc;

  f32x4 acc[8][4];
  #pragma unroll
  for (int i=0;i<8;i++)
    #pragma unroll
    for (int j=0;j<4;j++) acc[i][j] = (f32x4){0.f,0.f,0.f,0.f};
  bf16x8 bF0, bF1, bF2, bF3;

  // prologue: stage lo(K0), hi(K0), lo(K1) = 6 half-tiles (12 calls);
  // vmcnt(8) retires the oldest 4 = lo(K0), exactly what p1 needs.
  STAGE_A(0,0); STAGE_B(0,0);
  STAGE_A(0,1); STAGE_B(0,1);
  STAGE_A(1,0); STAGE_B(1,0);
  VM8;
  __builtin_amdgcn_s_barrier();

  for (int j = 0; j < nIt-1; ++j){
    int k1 = 2*j+1, k2 = 2*j+2, k3 = 2*j+3;
    PHASE(0,0,0, STAGE_A(k1,1), NOWT);
    PHASE(0,0,1, STAGE_B(k1,1), VM8);
    PHASE(0,1,0, STAGE_A(k2,0), NOWT);
    PHASE(0,1,1, STAGE_B(k2,0), VM8);
    PHASE(1,0,0, STAGE_A(k2,1), NOWT);
    PHASE(1,0,1, STAGE_B(k2,1), VM8);
    PHASE(1,1,0, STAGE_A(k3,0), NOWT);
    PHASE(1,1,1, STAGE_B(k3,0), VM8);
  }
  { // final iteration: only hi(last) still needs staging (p1,p2).
    int kL = 2*nIt - 1;
    PHASE(0,0,0, STAGE_A(kL,1), NOWT);
    PHASE(0,0,1, STAGE_B(kL,1), VM8);
    PHASE(0,1,0, NOSTG, NOWT);
    PHASE(0,1,1, NOSTG, VM4);   // retire lo(odd) staged prev p7,p8
    PHASE(1,0,0, NOSTG, NOWT);
    PHASE(1,0,1, NOSTG, VM0);   // retire hi(last) staged this p1,p2
    PHASE(1,1,0, NOSTG, NOWT);
    PHASE(1,1,1, NOSTG, NOWT);
  }

  // epilogue: C/D layout col=lane&15, row=quad*4+e (m89/m91 verified)
  const float* lrow = lsum + b*T_;
  #pragma unroll
  for (int i=0;i<8;i++){
    float rl[4];
    #pragma unroll
    for (int e=0;e<4;e++)
      rl[e] = __builtin_amdgcn_rcpf(lrow[t0abs + wm*128 + i*16 + quad*4 + e]);
    #pragma unroll
    for (int j2=0;j2<4;j2++){
      int rcol = wn*64 + j2*16 + lc;
      #pragma unroll
      for (int e=0;e<4;e++){
        int t = t0abs + wm*128 + i*16 + quad*4 + e;
        out[(((long long)b*NS_ + jIdx)*T_ + t)*R_ + rcol] = acc[i][j2][e] * rl[e];
      }
    }
  }
}

// ------------------------------------------------------------------ proj
// proj[b][n][t] = sum_o VT[b][n*256+o][t] * wp[o] + bp  (coalesced over t)
__global__ __launch_bounds__(256)
void proj_kernel(const u16* __restrict__ VT, const float* __restrict__ wp,
                 const float* __restrict__ bp, float* __restrict__ proj){
  int gid = blockIdx.x*256 + threadIdx.x;   // 16*4*2048
  int bn = gid >> 11, t = gid & 2047;
  const u16* base = VT + (long long)bn*R_*T_ + t;
  float acc = bp[0];
  #pragma unroll 8
  for (int o=0;o<R_;o++)
    acc = fmaf(bf2f(base[(long long)o*T_]), wp[o], acc);
  proj[gid] = acc;
}

// ------------------------------------------------------- cov + loss
__global__ __launch_bounds__(256)
void loss_batch_kernel(const float* __restrict__ proj, float* __restrict__ partial){
  __shared__ float red[4][14];
  int tid = threadIdx.x, lane = tid & 63, wave = tid >> 6;
  int b = blockIdx.x;
  const float* pb = proj + b*NS_*T_;
  float s[14];
  #pragma unroll
  for (int kk=0;kk<14;kk++) s[kk]=0.0f;
  for (int t=tid; t<T_; t+=256){
    float x0 = pb[0*T_+t], x1 = pb[1*T_+t], x2 = pb[2*T_+t], x3 = pb[3*T_+t];
    s[0]+=x0; s[1]+=x1; s[2]+=x2; s[3]+=x3;
    s[4]+=x0*x0; s[5]+=x1*x0; s[6]+=x1*x1; s[7]+=x2*x0; s[8]+=x2*x1;
    s[9]+=x2*x2; s[10]+=x3*x0; s[11]+=x3*x1; s[12]+=x3*x2; s[13]+=x3*x3;
  }
  #pragma unroll
  for (int kk=0;kk<14;kk++){
    #pragma unroll
    for (int off=1; off<64; off<<=1)
      s[kk] += __shfl_xor(s[kk], off, 64);
  }
  if (lane == 0){
    #pragma unroll
    for (int kk=0;kk<14;kk++) red[wave][kk] = s[kk];
  }
  __syncthreads();
  if (tid == 0){
    float tot[14];
    #pragma unroll
    for (int kk=0;kk<14;kk++)
      tot[kk] = red[0][kk] + red[1][kk] + red[2][kk] + red[3][kk];
    const float invT  = 1.0f/(float)T_;
    const float invT1 = 1.0f/(float)(T_-1);
    float csum = 0.0f;
    #pragma unroll
    for (int n=0;n<4;n++){
      #pragma unroll
      for (int m=0;m<=n;m++){
        int id = n*(n+1)/2 + m;
        float c = (tot[4+id] - tot[n]*tot[m]*invT) * invT1;
        csum += (n==m) ? fabsf(c) : 2.0f*fabsf(c);
      }
    }
    partial[b] = 0.5f*csum;
  }
}

__global__ void loss_final_kernel(const float* __restrict__ partial,
                                  float* __restrict__ simOut){
  if (threadIdx.x == 0){
    float sim = 0.0f;
    #pragma unroll
    for (int b=0;b<B_;b++) sim += partial[b];
    simOut[0] = sim * (1.0f/(float)B_);
  }
}

// ----------------------------------------------------------------- launch
extern "C" void kernel_launch(void* const* d_in, const int* in_sizes, int n_in,
                              void* d_out, int out_size, void* d_ws, size_t ws_size,
                              hipStream_t stream)
{
  const float* q  = (const float*)d_in[0];
  const float* k  = (const float*)d_in[1];
  const float* v  = (const float*)d_in[2];
  const float* wq = (const float*)d_in[3];
  const float* bq = (const float*)d_in[4];
  const float* wk = (const float*)d_in[5];
  const float* bk = (const float*)d_in[6];
  const float* wv = (const float*)d_in[7];
  const float* bv = (const float*)d_in[8];
  const float* wp = (const float*)d_in[9];
  const float* bp = (const float*)d_in[10];
  float* out = (float*)d_out;

  // workspace layout (bytes); total ~286.6 MB
  char* ws = (char*)d_ws;
  u16* qbf   = (u16*)(ws + 0);          // 16 MB  (dead after qp GEMM)
  u16* kbf   = (u16*)(ws + 16777216);   // 16 MB  (dead after kp GEMM)
  u16* vbf   = (u16*)(ws + 33554432);   // 16 MB
  u16* wqbf  = (u16*)(ws + 50331648);   // 128 KB
  u16* wkbf  = (u16*)(ws + 50462720);   // 128 KB
  u16* wvbf  = (u16*)(ws + 50593792);   // 512 KB
  u16* qpbf  = (u16*)(ws + 51118080);   // 16 MB  [B*T][R] bf16
  u16* kpbf  = (u16*)(ws + 67895296);   // 16 MB
  u16* vtbf  = (u16*)(ws + 84672512);   // 64 MB  [B][NS*R][T] bf16 (vs^T, +bias)
  u16* pbuf  = (u16*)(ws + 151781376);  // 128 MB [B][T][T] bf16 (p' = exp(v))
  float* prj = (float*)(ws + 285999104);// 512 KB [B][NS][T] f32
  float* lpart = (float*)(ws + 0);      // 64 B, reuses dead qbf region
  float* lsum  = (float*)(ws + 16777216); // 128 KB [B][T] f32, reuses dead kbf

  // 0) fp32 -> bf16 conversions
  cvt_kernel<<<8192,256,0,stream>>>(q,  qbf, 2097152);
  cvt_kernel<<<8192,256,0,stream>>>(k,  kbf, 2097152);
  cvt_kernel<<<8192,256,0,stream>>>(v,  vbf, 2097152);
  cvt_kernel<<<64,  256,0,stream>>>(wq, wqbf, 16384);
  cvt_kernel<<<64,  256,0,stream>>>(wk, wkbf, 16384);
  cvt_kernel<<<256, 256,0,stream>>>(wv, wvbf, 65536);

  // 1) projections: qp = q@wq^T+bq, kp = k@wk^T+bk  (M=32768,N=256,K=256)
  dim3 gq(2,256,1);
  gemm_nt_bias<<<gq,256,0,stream>>>(qbf, wqbf, qpbf, bq, 256,256,256,256, 0,0,0, 0, 0);
  gemm_nt_bias<<<gq,256,0,stream>>>(kbf, wkbf, kpbf, bk, 256,256,256,256, 0,0,0, 0, 0);
  // vs^T: per (b,n): C[o][t] = wv[n] @ v[b]^T + bv[n]  (M=256,N=2048,K=256)
  dim3 gv(16,2,64);
  gemm_nt_bias<<<gv,256,0,stream>>>(wvbf, vbf, vtbf, bv, 256,256,2048,256,
                                    65536LL, 524288LL, 524288LL, 256, 1);

  // 2) zero l table + the P' strips pv's 256-row tiles read but attn
  //    never writes; then single-sweep attention
  zero_kernel<<<128,256,0,stream>>>(lsum, 32768);
  pzero_kernel<<<128,256,0,stream>>>(pbuf);
  dim3 ga(272,16,1);
  attn_kernel<<<ga,256,0,stream>>>(qpbf, kpbf, pbuf, lsum);

  // 3) out = (P' @ Vcat) / l   (256^2 8-phase, XCD-grouped grid)
  pv_kernel<<<512,512,0,stream>>>(pbuf, vtbf, lsum, out);

  // 4) sim loss (proj -> per-batch cov partials -> final mean)
  proj_kernel<<<512,256,0,stream>>>(vtbf, wp, bp, prj);
  loss_batch_kernel<<<16,256,0,stream>>>(prj, lpart);
  loss_final_kernel<<<1,64,0,stream>>>(lpart, out + 33554432);
}

// Round 4
// 469.759 us; speedup vs baseline: 1.0269x; 1.0110x over previous
//
#include <hip/hip_runtime.h>

#define B_  16
#define T_  2048
#define R_  256
#define NS_ 4

typedef unsigned short u16;
typedef __attribute__((ext_vector_type(8))) __bf16 bf16x8;
typedef __attribute__((ext_vector_type(4))) float f32x4;

__device__ __forceinline__ u16 f2bf(float f){
  union { float f; unsigned u; } x; x.f = f;
  unsigned r = x.u + 0x7FFFu + ((x.u >> 16) & 1u);
  return (u16)(r >> 16);
}
__device__ __forceinline__ float bf2f(u16 h){
  union { unsigned u; float f; } x; x.u = ((unsigned)h) << 16; return x.f;
}

// async global->LDS, 16B per lane. LDS dest must be wave-uniform base; HW
// writes lane i at base + i*16 (guide §5). Our chunk order matches that.
__device__ __forceinline__ void async_cp16(const void* g, void* l){
  __builtin_amdgcn_global_load_lds((__attribute__((address_space(1))) void*)g,
                                   (__attribute__((address_space(3))) void*)l,
                                   16, 0, 0);
}

// ---------------------------------------------------------------- convert
__global__ __launch_bounds__(256)
void cvt_kernel(const float* __restrict__ src, u16* __restrict__ dst, int n4){
  int i = blockIdx.x*256 + threadIdx.x;
  if (i >= n4) return;
  float4 f = ((const float4*)src)[i];
  ushort4 o;
  o.x = f2bf(f.x); o.y = f2bf(f.y); o.z = f2bf(f.z); o.w = f2bf(f.w);
  ((ushort4*)dst)[i] = o;
}

__global__ __launch_bounds__(256)
void zero_kernel(float* __restrict__ p, int n){
  int i = blockIdx.x*256 + threadIdx.x;
  if (i < n) p[i] = 0.0f;
}

// Zero the above-diagonal strips of P' that the 256-row pv A-tiles read but
// attn never writes: per (b,tT): rows [256tT, 256tT+128) x cols
// [256tT+128, 256tT+256). 4 MB total.
__global__ __launch_bounds__(256)
void pzero_kernel(u16* __restrict__ P){
  int blk = blockIdx.x;            // 0..127
  int b = blk & 15, tT = blk >> 4; // tT 0..7
  long long base = (long long)b*T_*T_ + (long long)(tT*256)*T_ + (tT*256 + 128);
  int r = threadIdx.x >> 1, h = threadIdx.x & 1;
  u16* p = P + base + (long long)r*T_ + h*64;
  uint4 z = {0u,0u,0u,0u};
  #pragma unroll
  for (int i=0;i<8;i++) ((uint4*)p)[i] = z;
}

// ------------------------------------------------- generic NT GEMM (bf16)
// C[m][n] = sum_k A[m][k]*B[n][k] + bias ; C stored bf16.
// z decode: n = z&3 (weight/bias select), b = z>>2 (batch select).
// biasMode 0: bias indexed by col (N). biasMode 1: bias indexed by row (M).
__global__ __launch_bounds__(256, 2)
void gemm_nt_bias(const u16* __restrict__ A, const u16* __restrict__ Bm,
                  u16* __restrict__ C, const float* __restrict__ bias,
                  int lda, int ldb, int ldc, int K,
                  long long sAn, long long sBb, long long sCz,
                  int sBiasN, int biasMode)
{
  __shared__ __align__(16) u16 As[128*32];
  __shared__ __align__(16) u16 Bs[128*32];
  int tid = threadIdx.x;
  int lane = tid & 63, wave = tid >> 6;
  int z = blockIdx.z;
  int nIdx = z & 3, bIdx = z >> 2;
  A    += (long long)nIdx * sAn;
  Bm   += (long long)bIdx * sBb;
  C    += (long long)z * sCz;
  bias += (long long)nIdx * sBiasN;
  int mBase = blockIdx.y * 128;
  int nBase = blockIdx.x * 128;
  int wm = (wave >> 1) * 64, wn = (wave & 1) * 64;
  int quad = lane >> 4, lc = lane & 15;

  f32x4 acc[4][4];
  #pragma unroll
  for (int i=0;i<4;i++)
    #pragma unroll
    for (int j=0;j<4;j++) acc[i][j] = (f32x4){0.f,0.f,0.f,0.f};

  for (int k0=0; k0<K; k0+=32){
    #pragma unroll
    for (int r=0;r<2;r++){
      int c = r*256 + tid;
      int row = c >> 2, col = (c & 3)*8;
      async_cp16(A  + (long long)(mBase+row)*lda + k0 + col, (void*)(As + (r*256 + wave*64)*8));
      async_cp16(Bm + (long long)(nBase+row)*ldb + k0 + col, (void*)(Bs + (r*256 + wave*64)*8));
    }
    __syncthreads();
    bf16x8 af[4], bfr[4];
    #pragma unroll
    for (int i=0;i<4;i++){
      af[i]  = *(const bf16x8*)(As + (wm + i*16 + lc)*32 + quad*8);
      bfr[i] = *(const bf16x8*)(Bs + (wn + i*16 + lc)*32 + quad*8);
    }
    #pragma unroll
    for (int i=0;i<4;i++)
      #pragma unroll
      for (int j=0;j<4;j++)
        acc[i][j] = __builtin_amdgcn_mfma_f32_16x16x32_bf16(af[i], bfr[j], acc[i][j], 0,0,0);
    __syncthreads();
  }
  // epilogue: C/D layout col=lane&15, row=quad*4+e (m89/m91 verified)
  #pragma unroll
  for (int i=0;i<4;i++){
    #pragma unroll
    for (int j=0;j<4;j++){
      int colG = nBase + wn + j*16 + lc;
      float bc = (biasMode==0) ? bias[colG] : 0.0f;
      #pragma unroll
      for (int e=0;e<4;e++){
        int rowG = mBase + wm + i*16 + quad*4 + e;
        float val = acc[i][j][e] + ((biasMode==0) ? bc : bias[rowG]);
        C[(long long)rowG*ldc + colG] = f2bf(val);
      }
    }
  }
}

// ------------------------------------- attention scores, single sweep
// One block per (b, 64-row t-tile, 128-col s-tile). No max subtraction:
// scores here are bounded (|v| ~< 10 << 88), so p' = exp(v) is overflow-safe
// and softmax = p'/sum(p') exactly. Masked (s>t or v==0) -> exp(-10000) = 0
// in fp32, matching the reference tril+where quirk. Row sums accumulate via
// fp32 atomicAdd into l[B][T]; pv_kernel divides by l in its epilogue.
__global__ __launch_bounds__(256, 4)
void attn_kernel(const u16* __restrict__ qp, const u16* __restrict__ kp,
                 u16* __restrict__ P, float* __restrict__ lsum)
{
  __shared__ __align__(16) u16 Qs[64*32];
  __shared__ __align__(16) u16 Ks[128*32];
  int tid = threadIdx.x, lane = tid & 63, wave = tid >> 6;
  int b = blockIdx.y;
  // heavy-first flat decode: t64 descending, c(t64)=t64/2+1 s-tiles
  int f = blockIdx.x;
  int t64 = 31;
  while (f >= (t64 >> 1) + 1){ f -= (t64 >> 1) + 1; t64--; }
  int sT = f;
  int tBase = t64 * 64;
  const u16* Q  = qp + ((long long)b*T_ + tBase) * R_;
  const u16* Kt = kp + (long long)b*T_*R_ + (long long)sT*128*R_;
  u16* Pb = P + (long long)b*T_*T_;
  const float scale = 0.0625f;     // 1/sqrt(256)
  int quad = lane >> 4, lc = lane & 15;
  int rowLoc = wave*16 + quad*4;

  f32x4 acc[8];
  #pragma unroll
  for (int j=0;j<8;j++) acc[j] = (f32x4){0.f,0.f,0.f,0.f};

  for (int k0=0;k0<R_;k0+=32){
    {
      int row = tid >> 2, col = (tid & 3)*8;
      async_cp16(Q + (long long)row*R_ + k0 + col, (void*)(Qs + (wave*64)*8));
    }
    #pragma unroll
    for (int r=0;r<2;r++){
      int c = r*256 + tid;
      int row = c >> 2, col = (c & 3)*8;
      async_cp16(Kt + (long long)row*R_ + k0 + col, (void*)(Ks + (r*256 + wave*64)*8));
    }
    __syncthreads();
    bf16x8 aq = *(const bf16x8*)(Qs + (wave*16 + lc)*32 + quad*8);
    #pragma unroll
    for (int j=0;j<8;j++){
      bf16x8 bk = *(const bf16x8*)(Ks + (j*16 + lc)*32 + quad*8);
      acc[j] = __builtin_amdgcn_mfma_f32_16x16x32_bf16(aq, bk, acc[j], 0,0,0);
    }
    __syncthreads();
  }

  int sCol0 = sT*128 + lc;
  #pragma unroll
  for (int e=0;e<4;e++){
    int t = tBase + rowLoc + e;
    long long ro = (long long)t * T_;
    float rs = 0.0f;
    #pragma unroll
    for (int j=0;j<8;j++){
      float v = acc[j][e]*scale;
      int s = sCol0 + j*16;
      if (s > t || v == 0.0f) v = -10000.0f;
      float p = __expf(v);            // exact 0 when masked
      rs += p;
      Pb[ro + s] = f2bf(p);
    }
    // sum across the 16 lc-lanes of this quad (they hold cols of row t)
    #pragma unroll
    for (int off=1; off<16; off<<=1)
      rs += __shfl_xor(rs, off, 64);
    if (lc == 0)
      atomicAdd(&lsum[b*T_ + t], rs);
  }
}

// --------------------------------------------------------------- PV GEMM
// out[b][n][t][r] = (1/l[t]) * sum_s P'[b][t][s] * VT[b][n*256+r][s]
// 256x256 tile, BK=64, 8 waves (2Mx4N), 512 threads, 8 phases per 2 K-tiles.
// Fragment ds_reads pipelined one phase ahead (ping-pong regs); one barrier
// per phase.
// R3 FIX (cross-wave race): vmcnt is PER-WAVE, so a slot's producers must
// be retired by a wait executed by ALL waves in an EARLIER phase, with the
// phase barrier between retire and read. Waits now live in ODD phases as
// vmcnt(6) (after STAGE_A: 10 outstanding -> retire oldest 4 = exactly the
// A+B pair read at the end of the NEXT even phase). Ledger (steady): enter
// p1 with 8 in flight; p1 +2=10, VM6->6; p2 +2=8; repeat. Drain: VM6(p1),
// VM4(p3), VM0(p5). Never 0 in the main loop.
#define MF(A,Bx,C) __builtin_amdgcn_mfma_f32_16x16x32_bf16(A,Bx,C,0,0,0)
#define VM8 asm volatile("s_waitcnt vmcnt(8)" ::: "memory")
#define VM6 asm volatile("s_waitcnt vmcnt(6)" ::: "memory")
#define VM4 asm volatile("s_waitcnt vmcnt(4)" ::: "memory")
#define VM0 asm volatile("s_waitcnt vmcnt(0)" ::: "memory")

#define STAGE_A(KT,KH) do { \
  const u16* sp_ = aG + (int)((KT)*64 + (KH)*32); \
  u16* dp_ = (u16*)lds + (((KT)&1)*16384 + (KH)*8192 + wave*512); \
  async_cp16(sp_ + stOff, dp_); \
  async_cp16(sp_ + stOff + 128*2048, dp_ + 4096); \
} while(0)
#define STAGE_B(KT,KH) do { \
  const u16* sp_ = bG + (int)((KT)*64 + (KH)*32); \
  u16* dp_ = (u16*)lds + (32768 + ((KT)&1)*16384 + (KH)*8192 + wave*512); \
  async_cp16(sp_ + stOff, dp_); \
  async_cp16(sp_ + stOff + 4096*... , dp_); \
} while(0)
#undef STAGE_B
#define STAGE_B(KT,KH) do { \
  const u16* sp_ = bG + (int)((KT)*64 + (KH)*32); \
  u16* dp_ = (u16*)lds + (32768 + ((KT)&1)*16384 + (KH)*8192 + wave*512); \
  async_cp16(sp_ + stOff, dp_); \
  async_cp16(sp_ + stOff + 128*2048, dp_ + 4096); \
} while(0)

#define LDA_F(BUF,KH,CU,TI) (*(const bf16x8*)(&lds[(BUF)*16384 + (KH)*8192 + (rbA + (CU)*64 + (TI)*16)*32 + qSw]))
#define LDB_F(BUF,KH,JJ)    (*(const bf16x8*)(&lds[32768 + (BUF)*16384 + (KH)*8192 + (rbB + (JJ)*16)*32 + qSw]))

#define RD_A(D0,D1,D2,D3,BUF,KH,CU) do { \
  D0 = LDA_F(BUF,KH,CU,0); D1 = LDA_F(BUF,KH,CU,1); \
  D2 = LDA_F(BUF,KH,CU,2); D3 = LDA_F(BUF,KH,CU,3); } while(0)
#define RD_B(D0,D1,D2,D3,BUF,KH) do { \
  D0 = LDB_F(BUF,KH,0); D1 = LDB_F(BUF,KH,1); \
  D2 = LDB_F(BUF,KH,2); D3 = LDB_F(BUF,KH,3); } while(0)

// Phase: wait prefetched frags -> MFMA cluster -> issue next-phase work
// (stage/reads/vmcnt per ledger) -> single barrier.
#define PH(CU,A0,A1,A2,A3,Q0,Q1,Q2,Q3,...) do { \
  asm volatile("s_waitcnt lgkmcnt(0)" ::: "memory"); \
  __builtin_amdgcn_sched_barrier(0); \
  __builtin_amdgcn_s_setprio(1); \
  acc[(CU)*4+0][0]=MF(A0,Q0,acc[(CU)*4+0][0]); \
  acc[(CU)*4+0][1]=MF(A0,Q1,acc[(CU)*4+0][1]); \
  acc[(CU)*4+0][2]=MF(A0,Q2,acc[(CU)*4+0][2]); \
  acc[(CU)*4+0][3]=MF(A0,Q3,acc[(CU)*4+0][3]); \
  acc[(CU)*4+1][0]=MF(A1,Q0,acc[(CU)*4+1][0]); \
  acc[(CU)*4+1][1]=MF(A1,Q1,acc[(CU)*4+1][1]); \
  acc[(CU)*4+1][2]=MF(A1,Q2,acc[(CU)*4+1][2]); \
  acc[(CU)*4+1][3]=MF(A1,Q3,acc[(CU)*4+1][3]); \
  acc[(CU)*4+2][0]=MF(A2,Q0,acc[(CU)*4+2][0]); \
  acc[(CU)*4+2][1]=MF(A2,Q1,acc[(CU)*4+2][1]); \
  acc[(CU)*4+2][2]=MF(A2,Q2,acc[(CU)*4+2][2]); \
  acc[(CU)*4+2][3]=MF(A2,Q3,acc[(CU)*4+2][3]); \
  acc[(CU)*4+3][0]=MF(A3,Q0,acc[(CU)*4+3][0]); \
  acc[(CU)*4+3][1]=MF(A3,Q1,acc[(CU)*4+3][1]); \
  acc[(CU)*4+3][2]=MF(A3,Q2,acc[(CU)*4+3][2]); \
  acc[(CU)*4+3][3]=MF(A3,Q3,acc[(CU)*4+3][3]); \
  __builtin_amdgcn_s_setprio(0); \
  __VA_ARGS__ \
  asm volatile("" ::: "memory"); \
  __builtin_amdgcn_s_barrier(); \
} while(0)

__global__ __launch_bounds__(512, 2)
void pv_kernel(const u16* __restrict__ P, const u16* __restrict__ VT,
               const float* __restrict__ lsum, float* __restrict__ out)
{
  __shared__ __align__(16) u16 lds[65536];   // 128 KB
  int tid = threadIdx.x, lane = tid & 63, wave = tid >> 6;
  // grid: 512 blocks. xcd = f&7; group g = (b,tT) with its 4 j-blocks on
  // adjacent dispatch slots of the same xcd slot (P-tile L2 reuse);
  // tT descending with dispatch (heavy-first, greedy-balanced).
  int f = blockIdx.x;
  int xcd = f & 7, s = f >> 3;
  int g = xcd + 8*(s >> 2);     // 0..127
  int jIdx = s & 3;             // 0..3 -> n index
  int b = g & 15;
  int tT = 7 - (g >> 4);        // 0..7, heavy first
  int t0abs = tT * 256;
  int nIt = 2*(tT + 1);         // iterations; K = 256*(tT+1)

  const u16* aG = P  + (long long)b*T_*T_ + (long long)t0abs*T_;
  const u16* bG = VT + (long long)b*1024*T_ + (long long)(jIdx*256)*T_;

  // staging per-lane constants: lane L writes LDS chunk (L&3) of row L>>2;
  // fetch global chunk (L&3)^v(row) so LDS slot (r,c) holds chunk c^v(r).
  int stRow = tid >> 2;
  int vSt = (stRow & 3) ^ ((stRow >> 2) & 3);
  int stOff = stRow*2048 + (((tid & 3) ^ vSt) << 3);

  // read-side per-lane constants
  int quad = lane >> 4, lc = lane & 15;
  int wm = wave >> 2, wn = wave & 3;             // 2M x 4N waves
  int vlc = (lc & 3) ^ ((lc >> 2) & 3);          // == v(row) for all frag rows
  int qSw = ((quad ^ vlc) << 3);
  int rbA = wm*128 + lc;
  int rbB = wn*64 + lc;

  f32x4 acc[8][4];
  #pragma unroll
  for (int i=0;i<8;i++)
    #pragma unroll
    for (int j=0;j<4;j++) acc[i][j] = (f32x4){0.f,0.f,0.f,0.f};
  // ping-pong fragment registers: odd phases use fA, even use gA;
  // B pairs alternate bX (p1p2,p5p6) / bY (p3p4,p7p8).
  bf16x8 fA0,fA1,fA2,fA3, gA0,gA1,gA2,gA3;
  bf16x8 bX0,bX1,bX2,bX3, bY0,bY1,bY2,bY3;

  // prologue: stage (0,h0),(0,h1),(1,h0) = 12 loads; vmcnt(8) retires the
  // oldest 4 = (0,h0) A+B BEFORE the barrier -> cross-wave safe for the
  // post-barrier read.
  STAGE_A(0,0); STAGE_B(0,0);
  STAGE_A(0,1); STAGE_B(0,1);
  STAGE_A(1,0); STAGE_B(1,0);
  VM8;
  __builtin_amdgcn_s_barrier();
  RD_A(fA0,fA1,fA2,fA3, 0,0,0);
  RD_B(bX0,bX1,bX2,bX3, 0,0);

  for (int j = 0; j < nIt-1; ++j){
    int k1 = 2*j+1, k2 = 2*j+2, k3 = 2*j+3;
    PH(0, fA0,fA1,fA2,fA3, bX0,bX1,bX2,bX3,
       RD_A(gA0,gA1,gA2,gA3, 0,0,1); STAGE_A(k1,1); VM6; );
    PH(1, gA0,gA1,gA2,gA3, bX0,bX1,bX2,bX3,
       STAGE_B(k1,1);
       RD_A(fA0,fA1,fA2,fA3, 0,1,0); RD_B(bY0,bY1,bY2,bY3, 0,1); );
    PH(0, fA0,fA1,fA2,fA3, bY0,bY1,bY2,bY3,
       RD_A(gA0,gA1,gA2,gA3, 0,1,1); STAGE_A(k2,0); VM6; );
    PH(1, gA0,gA1,gA2,gA3, bY0,bY1,bY2,bY3,
       STAGE_B(k2,0);
       RD_A(fA0,fA1,fA2,fA3, 1,0,0); RD_B(bX0,bX1,bX2,bX3, 1,0); );
    PH(0, fA0,fA1,fA2,fA3, bX0,bX1,bX2,bX3,
       RD_A(gA0,gA1,gA2,gA3, 1,0,1); STAGE_A(k2,1); VM6; );
    PH(1, gA0,gA1,gA2,gA3, bX0,bX1,bX2,bX3,
       STAGE_B(k2,1);
       RD_A(fA0,fA1,fA2,fA3, 1,1,0); RD_B(bY0,bY1,bY2,bY3, 1,1); );
    PH(0, fA0,fA1,fA2,fA3, bY0,bY1,bY2,bY3,
       RD_A(gA0,gA1,gA2,gA3, 1,1,1); STAGE_A(k3,0); VM6; );
    PH(1, gA0,gA1,gA2,gA3, bY0,bY1,bY2,bY3,
       STAGE_B(k3,0);
       RD_A(fA0,fA1,fA2,fA3, 0,0,0); RD_B(bX0,bX1,bX2,bX3, 0,0); );
  }
  { // final iteration: only (last,h1) still needs staging.
    // Drain ledger: enter 8; p1 +2=10 VM6->6; p2 +2=8; p3 VM4->4; p5 VM0.
    int kL = 2*nIt - 1;
    PH(0, fA0,fA1,fA2,fA3, bX0,bX1,bX2,bX3,
       RD_A(gA0,gA1,gA2,gA3, 0,0,1); STAGE_A(kL,1); VM6; );
    PH(1, gA0,gA1,gA2,gA3, bX0,bX1,bX2,bX3,
       STAGE_B(kL,1);
       RD_A(fA0,fA1,fA2,fA3, 0,1,0); RD_B(bY0,bY1,bY2,bY3, 0,1); );
    PH(0, fA0,fA1,fA2,fA3, bY0,bY1,bY2,bY3,
       RD_A(gA0,gA1,gA2,gA3, 0,1,1); VM4; );
    PH(1, gA0,gA1,gA2,gA3, bY0,bY1,bY2,bY3,
       RD_A(fA0,fA1,fA2,fA3, 1,0,0); RD_B(bX0,bX1,bX2,bX3, 1,0); );
    PH(0, fA0,fA1,fA2,fA3, bX0,bX1,bX2,bX3,
       RD_A(gA0,gA1,gA2,gA3, 1,0,1); VM0; );
    PH(1, gA0,gA1,gA2,gA3, bX0,bX1,bX2,bX3,
       RD_A(fA0,fA1,fA2,fA3, 1,1,0); RD_B(bY0,bY1,bY2,bY3, 1,1); );
    PH(0, fA0,fA1,fA2,fA3, bY0,bY1,bY2,bY3,
       RD_A(gA0,gA1,gA2,gA3, 1,1,1); );
    PH(1, gA0,gA1,gA2,gA3, bY0,bY1,bY2,bY3, );
  }

  // epilogue: C/D layout col=lane&15, row=quad*4+e (m89/m91 verified)
  const float* lrow = lsum + b*T_;
  #pragma unroll
  for (int i=0;i<8;i++){
    float rl[4];
    #pragma unroll
    for (int e=0;e<4;e++)
      rl[e] = __builtin_amdgcn_rcpf(lrow[t0abs + wm*128 + i*16 + quad*4 + e]);
    #pragma unroll
    for (int j2=0;j2<4;j2++){
      int rcol = wn*64 + j2*16 + lc;
      #pragma unroll
      for (int e=0;e<4;e++){
        int t = t0abs + wm*128 + i*16 + quad*4 + e;
        out[(((long long)b*NS_ + jIdx)*T_ + t)*R_ + rcol] = acc[i][j2][e] * rl[e];
      }
    }
  }
}

// ------------------------------------------------------------------ proj
// proj[b][n][t] = sum_o VT[b][n*256+o][t] * wp[o] + bp  (coalesced over t)
__global__ __launch_bounds__(256)
void proj_kernel(const u16* __restrict__ VT, const float* __restrict__ wp,
                 const float* __restrict__ bp, float* __restrict__ proj){
  int gid = blockIdx.x*256 + threadIdx.x;   // 16*4*2048
  int bn = gid >> 11, t = gid & 2047;
  const u16* base = VT + (long long)bn*R_*T_ + t;
  float acc = bp[0];
  #pragma unroll 8
  for (int o=0;o<R_;o++)
    acc = fmaf(bf2f(base[(long long)o*T_]), wp[o], acc);
  proj[gid] = acc;
}

// ------------------------------------------------------- cov + loss
__global__ __launch_bounds__(256)
void loss_batch_kernel(const float* __restrict__ proj, float* __restrict__ partial){
  __shared__ float red[4][14];
  int tid = threadIdx.x, lane = tid & 63, wave = tid >> 6;
  int b = blockIdx.x;
  const float* pb = proj + b*NS_*T_;
  float s[14];
  #pragma unroll
  for (int kk=0;kk<14;kk++) s[kk]=0.0f;
  for (int t=tid; t<T_; t+=256){
    float x0 = pb[0*T_+t], x1 = pb[1*T_+t], x2 = pb[2*T_+t], x3 = pb[3*T_+t];
    s[0]+=x0; s[1]+=x1; s[2]+=x2; s[3]+=x3;
    s[4]+=x0*x0; s[5]+=x1*x0; s[6]+=x1*x1; s[7]+=x2*x0; s[8]+=x2*x1;
    s[9]+=x2*x2; s[10]+=x3*x0; s[11]+=x3*x1; s[12]+=x3*x2; s[13]+=x3*x3;
  }
  #pragma unroll
  for (int kk=0;kk<14;kk++){
    #pragma unroll
    for (int off=1; off<64; off<<=1)
      s[kk] += __shfl_xor(s[kk], off, 64);
  }
  if (lane == 0){
    #pragma unroll
    for (int kk=0;kk<14;kk++) red[wave][kk] = s[kk];
  }
  __syncthreads();
  if (tid == 0){
    float tot[14];
    #pragma unroll
    for (int kk=0;kk<14;kk++)
      tot[kk] = red[0][kk] + red[1][kk] + red[2][kk] + red[3][kk];
    const float invT  = 1.0f/(float)T_;
    const float invT1 = 1.0f/(float)(T_-1);
    float csum = 0.0f;
    #pragma unroll
    for (int n=0;n<4;n++){
      #pragma unroll
      for (int m=0;m<=n;m++){
        int id = n*(n+1)/2 + m;
        float c = (tot[4+id] - tot[n]*tot[m]*invT) * invT1;
        csum += (n==m) ? fabsf(c) : 2.0f*fabsf(c);
      }
    }
    partial[b] = 0.5f*csum;
  }
}

__global__ void loss_final_kernel(const float* __restrict__ partial,
                                  float* __restrict__ simOut){
  if (threadIdx.x == 0){
    float sim = 0.0f;
    #pragma unroll
    for (int b=0;b<B_;b++) sim += partial[b];
    simOut[0] = sim * (1.0f/(float)B_);
  }
}

// ----------------------------------------------------------------- launch
extern "C" void kernel_launch(void* const* d_in, const int* in_sizes, int n_in,
                              void* d_out, int out_size, void* d_ws, size_t ws_size,
                              hipStream_t stream)
{
  const float* q  = (const float*)d_in[0];
  const float* k  = (const float*)d_in[1];
  const float* v  = (const float*)d_in[2];
  const float* wq = (const float*)d_in[3];
  const float* bq = (const float*)d_in[4];
  const float* wk = (const float*)d_in[5];
  const float* bk = (const float*)d_in[6];
  const float* wv = (const float*)d_in[7];
  const float* bv = (const float*)d_in[8];
  const float* wp = (const float*)d_in[9];
  const float* bp = (const float*)d_in[10];
  float* out = (float*)d_out;

  // workspace layout (bytes); total ~286.6 MB
  char* ws = (char*)d_ws;
  u16* qbf   = (u16*)(ws + 0);          // 16 MB  (dead after qp GEMM)
  u16* kbf   = (u16*)(ws + 16777216);   // 16 MB  (dead after kp GEMM)
  u16* vbf   = (u16*)(ws + 33554432);   // 16 MB
  u16* wqbf  = (u16*)(ws + 50331648);   // 128 KB
  u16* wkbf  = (u16*)(ws + 50462720);   // 128 KB
  u16* wvbf  = (u16*)(ws + 50593792);   // 512 KB
  u16* qpbf  = (u16*)(ws + 51118080);   // 16 MB  [B*T][R] bf16
  u16* kpbf  = (u16*)(ws + 67895296);   // 16 MB
  u16* vtbf  = (u16*)(ws + 84672512);   // 64 MB  [B][NS*R][T] bf16 (vs^T, +bias)
  u16* pbuf  = (u16*)(ws + 151781376);  // 128 MB [B][T][T] bf16 (p' = exp(v))
  float* prj = (float*)(ws + 285999104);// 512 KB [B][NS][T] f32
  float* lpart = (float*)(ws + 0);      // 64 B, reuses dead qbf region
  float* lsum  = (float*)(ws + 16777216); // 128 KB [B][T] f32, reuses dead kbf

  // 0) fp32 -> bf16 conversions
  cvt_kernel<<<8192,256,0,stream>>>(q,  qbf, 2097152);
  cvt_kernel<<<8192,256,0,stream>>>(k,  kbf, 2097152);
  cvt_kernel<<<8192,256,0,stream>>>(v,  vbf, 2097152);
  cvt_kernel<<<64,  256,0,stream>>>(wq, wqbf, 16384);
  cvt_kernel<<<64,  256,0,stream>>>(wk, wkbf, 16384);
  cvt_kernel<<<256, 256,0,stream>>>(wv, wvbf, 65536);

  // 1) projections: qp = q@wq^T+bq, kp = k@wk^T+bk  (M=32768,N=256,K=256)
  dim3 gq(2,256,1);
  gemm_nt_bias<<<gq,256,0,stream>>>(qbf, wqbf, qpbf, bq, 256,256,256,256, 0,0,0, 0, 0);
  gemm_nt_bias<<<gq,256,0,stream>>>(kbf, wkbf, kpbf, bk, 256,256,256,256, 0,0,0, 0, 0);
  // vs^T: per (b,n): C[o][t] = wv[n] @ v[b]^T + bv[n]  (M=256,N=2048,K=256)
  dim3 gv(16,2,64);
  gemm_nt_bias<<<gv,256,0,stream>>>(wvbf, vbf, vtbf, bv, 256,256,2048,256,
                                    65536LL, 524288LL, 524288LL, 256, 1);

  // 2) zero l table + the P' strips pv's 256-row tiles read but attn
  //    never writes; then single-sweep attention
  zero_kernel<<<128,256,0,stream>>>(lsum, 32768);
  pzero_kernel<<<128,256,0,stream>>>(pbuf);
  dim3 ga(272,16,1);
  attn_kernel<<<ga,256,0,stream>>>(qpbf, kpbf, pbuf, lsum);

  // 3) out = (P' @ Vcat) / l   (256^2 phase-pipelined, XCD-grouped grid)
  pv_kernel<<<512,512,0,stream>>>(pbuf, vtbf, lsum, out);

  // 4) sim loss (proj -> per-batch cov partials -> final mean)
  proj_kernel<<<512,256,0,stream>>>(vtbf, wp, bp, prj);
  loss_batch_kernel<<<16,256,0,stream>>>(prj, lpart);
  loss_final_kernel<<<1,64,0,stream>>>(lpart, out + 33554432);
}